// Round 4
// baseline (450.072 us; speedup 1.0000x reference)
//
#include <hip/hip_runtime.h>

typedef unsigned int uu32;

#define NN 14      // nodes
#define FD 24      // SEQ / feature dim
#define HD 64      // GAT hidden
#define NE 70      // 56 edges + 14 self loops
#define BB 32768   // batch
#define SPW 4      // samples per wave
#define WPB 4      // waves per block
#define K1_BLOCKS (BB / (WPB * SPW))   // 2048
#define K2_BLOCKS (NN * (BB / 256))    // 1792 (1 row/thread)
#define HAP 68     // padded row stride for H1 (16B-aligned rows)
#define H2P 24     // row stride for H2
#define PSZ 224    // dense P rows: 14*16

// Wave-local LDS sync (each wave owns a private slice inside the loop).
#define WSYNC() asm volatile("s_waitcnt lgkmcnt(0)" ::: "memory")

// readlane: pure-VALU wave broadcast (no LDS pipe). ALWAYS literal lane.
__device__ __forceinline__ float rdl(float v, int l) {
    union { float f; int i; } u;
    u.f = v;
    u.i = __builtin_amdgcn_readlane(u.i, l);
    return u.f;
}

// GAT stage. LDS census said S6's 112 broadcast ds_read_b128 per wave-sample
// was ~47% of the (binding) LDS-pipe cycles; it is now a literal-lane
// readlane stream over acc2 registers (A1 never touches LDS), which also
// gives every lane the full H2 column f2 in regs -> S9's LDS gather gone.
__global__ __launch_bounds__(256) void gat_k(
    const float* __restrict__ x, const int* __restrict__ ei,
    const float* __restrict__ W1, const float* __restrict__ as1,
    const float* __restrict__ ad1, const float* __restrict__ b1,
    const float* __restrict__ W2, const float* __restrict__ as2,
    const float* __restrict__ ad2, const float* __restrict__ b2,
    float* __restrict__ Gout) {
    __shared__ __align__(16) float HA[WPB][NN * HAP];   // H1 only now
    __shared__ __align__(16) float H2S[WPB][NN * H2P];
    __shared__ __align__(16) float PS[WPB][PSZ];        // unnormalized exp rows
    __shared__ float sdS[WPB][2 * NN];                  // src/dst dots
    __shared__ float smS[WPB][NN];                      // per-dst exp sums
    __shared__ __align__(16) float a1S[2 * HD];
    __shared__ __align__(16) float a2S[2 * FD];
    __shared__ int esS[NE], edS[NE];

    const int tid = threadIdx.x;
    const int wv = tid >> 6;
    const int lane = tid & 63;
    float* HAw = HA[wv];
    float* H2w = H2S[wv];
    float* Pw = PS[wv];
    float* sdw = sdS[wv];
    float* smw = smS[wv];

    if (tid < 2 * HD) a1S[tid] = (tid < HD) ? as1[tid] : ad1[tid - HD];
    if (tid < 2 * FD) a2S[tid] = (tid < FD) ? as2[tid] : ad2[tid - FD];
    // edge staging: robust to int64 (lo/hi dword pairs) or int32 delivery
    if (tid < 56) {
        int e64 = 1;
        for (int i = 0; i < 8; i++)
            if (ei[2 * i + 1] != 0 || (uu32)ei[2 * i] >= (uu32)NN) e64 = 0;
        esS[tid] = e64 ? ei[2 * tid] : ei[tid];
        edS[tid] = e64 ? ei[112 + 2 * tid] : ei[56 + tid];
    } else if (tid < NE) {
        esS[tid] = tid - 56;   // self loops
        edS[tid] = tid - 56;
    }

    // per-lane resident weights
    float w1r[FD];
#pragma unroll
    for (int f = 0; f < FD; f++) w1r[f] = W1[f * HD + lane];
    const float b1r = b1[lane];
    const int f2 = lane % FD;
    const int g2 = lane / FD;      // 0,1 active for 24-wide stages
    float w2r[HD];
#pragma unroll
    for (int k = 0; k < HD; k++) w2r[k] = W2[k * FD + f2];
    const float b2r = b2[f2];
    __syncthreads();   // the ONE block barrier: cross-wave staged a1S/a2S/es/ed
    // edge ownership: edge0 = lane (0..63); lanes 0..5 also own 64..69
    const bool ex = (lane < NE - 64);
    const int s0 = esS[lane], d0 = edS[lane];
    const int s1 = esS[ex ? 64 + lane : 0], d1 = edS[ex ? 64 + lane : 0];

    const int gw = blockIdx.x * WPB + wv;
#pragma unroll 1
    for (int t = 0; t < SPW; t++) {
        const size_t b = (size_t)gw * SPW + t;
        // ---- 1. X[b] per-lane into regs (coalesced); no LDS staging ----
        const float* __restrict__ xb = x + b * (NN * FD);
        float xr[6];
        xr[0] = xb[lane];
        xr[1] = xb[64 + lane];
        xr[2] = xb[128 + lane];
        xr[3] = xb[192 + lane];
        xr[4] = xb[256 + lane];
        xr[5] = (lane < NN * FD - 320) ? xb[320 + lane] : 0.0f;
        // ---- 2. H1 = X @ W1 (lane owns hidden col); X via readlane ----
        float acc[NN];
#pragma unroll
        for (int n = 0; n < NN; n++) acc[n] = 0.0f;
#pragma unroll
        for (int f = 0; f < FD; f++) {
#pragma unroll
            for (int n = 0; n < NN; n++) {
                const int i = f * NN + n;          // compile-time
                acc[n] = fmaf(rdl(xr[i >> 6], i & 63), w1r[f], acc[n]);
            }
        }
#pragma unroll
        for (int n = 0; n < NN; n++) HAw[n * HAP + lane] = acc[n];
        WSYNC();
        // ---- 3. src/dst dots (28 lanes) + zero P/sums ----
        if (lane < 2 * NN) {
            const int v = (lane >= NN) ? 1 : 0;
            const int n2 = lane - v * NN;
            float s = 0.0f;
#pragma unroll
            for (int k = 0; k < 16; k++) {
                float4 h4 = *(const float4*)&HAw[n2 * HAP + 4 * k];
                float4 a4 = *(const float4*)&a1S[v * HD + 4 * k];
                s = fmaf(h4.x, a4.x, s); s = fmaf(h4.y, a4.y, s);
                s = fmaf(h4.z, a4.z, s); s = fmaf(h4.w, a4.w, s);
            }
            sdw[v * NN + n2] = s;
        }
        if (lane < PSZ / 4)
            *(float4*)&Pw[lane * 4] = make_float4(0.f, 0.f, 0.f, 0.f);
        if (lane < NN) smw[lane] = 0.0f;
        WSYNC();
        // ---- 4. softmax1 (shift-invariant, no max pass: |alpha| << 88) ----
        {
            float a = sdw[s0] + sdw[NN + d0];
            a = a > 0.0f ? a : 0.2f * a;               // leaky_relu(0.2)
            float e0 = __expf(a);
            atomicAdd(&smw[d0], e0);
            atomicAdd(&Pw[d0 * 16 + s0], e0);          // unnormalized
            if (ex) {
                a = sdw[s1] + sdw[NN + d1];
                a = a > 0.0f ? a : 0.2f * a;
                float e1 = __expf(a);
                atomicAdd(&smw[d1], e1);
                atomicAdd(&Pw[d1 * 16 + s1], e1);
            }
        }
        WSYNC();
        // ---- 5. A1 = ELU(P @ H1 / sum + b1); all register-resident ----
        const float pr0 = Pw[lane];
        const float pr1 = Pw[64 + lane];
        const float pr2 = Pw[128 + lane];
        const float pr3 = (lane < PSZ - 192) ? Pw[192 + lane] : 0.0f;
        const float smr = (lane < NN) ? smw[lane] : 1.0f;
        float acc2[NN];
#pragma unroll
        for (int n = 0; n < NN; n++) {
            float a = 0.0f;
#pragma unroll
            for (int k = 0; k < NN; k++) {
                const int i = n * 16 + k;          // compile-time
                const float pv = (i < 64) ? rdl(pr0, i) :
                                 (i < 128) ? rdl(pr1, i - 64) :
                                 (i < 192) ? rdl(pr2, i - 128) :
                                             rdl(pr3, i - 192);
                a = fmaf(pv, acc[k], a);
            }
            a = __fdividef(a, rdl(smr, n)) + b1r;
            acc2[n] = a > 0.0f ? a : (__expf(a) - 1.0f);   // ELU
        }
        // (A1 stays in acc2 registers; no LDS write)
        // ---- 6. H2 col f2 for ALL nodes, via literal readlane over acc2 ----
        float h2f[NN];
#pragma unroll
        for (int n = 0; n < NN; n++) h2f[n] = 0.0f;
#pragma unroll
        for (int k = 0; k < HD; k++) {
#pragma unroll
            for (int n = 0; n < NN; n++)
                h2f[n] = fmaf(rdl(acc2[n], k), w2r[k], h2f[n]);
        }
        if (lane < FD) {
#pragma unroll
            for (int n = 0; n < NN; n++) H2w[n * H2P + lane] = h2f[n];
        }
        WSYNC();
        // ---- 7. conv2 dots (28 lanes) + zero P/sums ----
        if (lane < 2 * NN) {
            const int v = (lane >= NN) ? 1 : 0;
            const int n2 = lane - v * NN;
            float s = 0.0f;
#pragma unroll
            for (int q = 0; q < 6; q++) {
                float4 h4 = *(const float4*)&H2w[n2 * H2P + 4 * q];
                float4 a4 = *(const float4*)&a2S[v * FD + 4 * q];
                s = fmaf(h4.x, a4.x, s); s = fmaf(h4.y, a4.y, s);
                s = fmaf(h4.z, a4.z, s); s = fmaf(h4.w, a4.w, s);
            }
            sdw[v * NN + n2] = s;
        }
        if (lane < PSZ / 4)
            *(float4*)&Pw[lane * 4] = make_float4(0.f, 0.f, 0.f, 0.f);
        if (lane < NN) smw[lane] = 0.0f;
        WSYNC();
        // ---- 8. softmax2 ----
        {
            float a = sdw[s0] + sdw[NN + d0];
            a = a > 0.0f ? a : 0.2f * a;
            float e0 = __expf(a);
            atomicAdd(&smw[d0], e0);
            atomicAdd(&Pw[d0 * 16 + s0], e0);
            if (ex) {
                a = sdw[s1] + sdw[NN + d1];
                a = a > 0.0f ? a : 0.2f * a;
                float e1 = __expf(a);
                atomicAdd(&smw[d1], e1);
                atomicAdd(&Pw[d1 * 16 + s1], e1);
            }
        }
        WSYNC();
        // ---- 9. G = P2 @ H2 / sum + b2 via rdl gather; h2f from regs ----
        {
            const float q0 = Pw[lane];
            const float q1 = Pw[64 + lane];
            const float q2 = Pw[128 + lane];
            const float q3 = (lane < PSZ - 192) ? Pw[192 + lane] : 0.0f;
            const float sr = (lane < NN) ? smw[lane] : 1.0f;
            float gv[NN];
#pragma unroll
            for (int n = 0; n < NN; n++) {
                float a = 0.0f;
#pragma unroll
                for (int m = 0; m < NN; m++) {
                    const int i = n * 16 + m;      // compile-time
                    const float pv = (i < 64) ? rdl(q0, i) :
                                     (i < 128) ? rdl(q1, i - 64) :
                                     (i < 192) ? rdl(q2, i - 128) :
                                                 rdl(q3, i - 192);
                    a = fmaf(pv, h2f[m], a);
                }
                gv[n] = __fdividef(a, rdl(sr, n)) + b2r;
            }
            // stores: literal node indices per branch (no runtime reg-index)
            if (g2 == 0) {
#pragma unroll
                for (int n = 0; n < 7; n++)
                    Gout[((size_t)n * BB + b) * FD + f2] = gv[n];
            } else if (g2 == 1) {
#pragma unroll
                for (int n = 7; n < NN; n++)
                    Gout[((size_t)n * BB + b) * FD + f2] = gv[n];
            }
        }
        WSYNC();   // protect reused LDS before next sample (wave-local)
    }
}

// MLP stage, in place on d_out. ZERO LDS, ZERO loops at runtime: lane l
// holds W1 column l (24 regs) and W2 row l (24 regs); the fully-unrolled
// j-loop broadcasts with LITERAL-lane v_readlane (the proven gat pattern;
// the round-3 regression came from RUNTIME lane indices in an unroll-1
// loop -> SGPR-hazard stalls). 1 row/thread keeps VGPR ~110 (4 waves/SIMD)
// and 1792 blocks for latency hiding. Straight-line ~6.2K instrs (~26KB,
// I$-resident).
__global__ __launch_bounds__(256) void mlp_k(
    const float* __restrict__ fc1w, const float* __restrict__ fc1b,
    const float* __restrict__ fc2w, const float* __restrict__ fc2b,
    float* __restrict__ gio) {
    const int t = threadIdx.x;
    const int lane = t & 63;
    const int n = blockIdx.x >> 7;             // 128 blocks per node
    const int b0 = (blockIdx.x & 127) * 256;

    const float* __restrict__ W1n = fc1w + (size_t)n * (FD * HD);  // [24][64]
    const float* __restrict__ W2n = fc2w + (size_t)n * (HD * FD);  // [64][24]

    // lane l: W1 column l (coalesced), W2 row l
    float w1c[FD], w2r[FD];
#pragma unroll
    for (int f = 0; f < FD; f++) w1c[f] = W1n[f * HD + lane];
#pragma unroll
    for (int f = 0; f < FD; f++) w2r[f] = W2n[lane * FD + f];
    const float b1r = fc1b[(size_t)n * HD + lane];
    const float b2r = (lane < FD) ? fc2b[(size_t)n * FD + lane] : 0.0f;

    const size_t base = ((size_t)n * BB + b0 + t) * FD;
    float g[FD], o[FD];
#pragma unroll
    for (int q = 0; q < 6; q++)
        *(float4*)&g[4 * q] = *(const float4*)&gio[base + 4 * q];
#pragma unroll
    for (int f = 0; f < FD; f++) o[f] = rdl(b2r, f);

#pragma unroll
    for (int j = 0; j < HD; j++) {             // FULLY unrolled: literal j
        float h = rdl(b1r, j);
#pragma unroll
        for (int f = 0; f < FD; f++)
            h = fmaf(g[f], rdl(w1c[f], j), h);
        h = fmaxf(h, 0.0f);
#pragma unroll
        for (int f = 0; f < FD; f++)
            o[f] = fmaf(h, rdl(w2r[f], j), o[f]);
    }
#pragma unroll
    for (int q = 0; q < 6; q++)
        *(float4*)&gio[base + 4 * q] = *(const float4*)&o[4 * q];
}

extern "C" void kernel_launch(void* const* d_in, const int* in_sizes, int n_in,
                              void* d_out, int out_size, void* d_ws, size_t ws_size,
                              hipStream_t stream) {
    (void)in_sizes; (void)n_in; (void)out_size; (void)d_ws; (void)ws_size;
    const float* x    = (const float*)d_in[0];
    const int*   ei   = (const int*)d_in[1];
    const float* W1   = (const float*)d_in[2];
    const float* as1  = (const float*)d_in[3];
    const float* ad1  = (const float*)d_in[4];
    const float* b1   = (const float*)d_in[5];
    const float* W2   = (const float*)d_in[6];
    const float* as2  = (const float*)d_in[7];
    const float* ad2  = (const float*)d_in[8];
    const float* b2   = (const float*)d_in[9];
    const float* fc1w = (const float*)d_in[10];
    const float* fc1b = (const float*)d_in[11];
    const float* fc2w = (const float*)d_in[12];
    const float* fc2b = (const float*)d_in[13];
    float* gio = (float*)d_out;   // G staged in d_out, MLP rewrites in place

    gat_k<<<dim3(K1_BLOCKS), dim3(256), 0, stream>>>(
        x, ei, W1, as1, ad1, b1, W2, as2, ad2, b2, gio);
    mlp_k<<<dim3(K2_BLOCKS), dim3(256), 0, stream>>>(
        fc1w, fc1b, fc2w, fc2b, gio);
}

// Round 6
// 344.581 us; speedup vs baseline: 1.3061x; 1.3061x over previous
//
#include <hip/hip_runtime.h>

typedef unsigned int uu32;

#define NN 14      // nodes
#define FD 24      // SEQ / feature dim
#define HD 64      // GAT hidden
#define NE 70      // 56 edges + 14 self loops
#define BB 32768   // batch
#define SPW 4      // samples per wave
#define WPB 4      // waves per block
#define K1_BLOCKS (BB / (WPB * SPW))   // 2048
#define K2_BLOCKS (NN * (BB / 256))    // 1792
#define HAP 68     // padded row stride for H1/A1 (16B-aligned rows)
#define H2P 24     // row stride for H2
#define PSZ 224    // dense P rows: 14*16

// Wave-local LDS sync (each wave owns a private slice inside the loop).
#define WSYNC() asm volatile("s_waitcnt lgkmcnt(0)" ::: "memory")

// readlane: pure-VALU wave broadcast. ONLY used at small scale with literal
// lane indices (S2/S5/S9 gathers) — bulk rdl streams measured ~4cy each
// (SGPR hazard) and regress vs the parallel LDS pipe (round-4 lesson).
__device__ __forceinline__ float rdl(float v, int l) {
    union { float f; int i; } u;
    u.f = v;
    u.i = __builtin_amdgcn_readlane(u.i, l);
    return u.f;
}

// GAT stage — round-3 structure (best measured: 197 us). LDS-pipe bound;
// S6's 112 broadcast b128 is the dataflow minimum (A1 = 896 floats, 4/read,
// 2 lane-groups sharing each instr).
__global__ __launch_bounds__(256) void gat_k(
    const float* __restrict__ x, const int* __restrict__ ei,
    const float* __restrict__ W1, const float* __restrict__ as1,
    const float* __restrict__ ad1, const float* __restrict__ b1,
    const float* __restrict__ W2, const float* __restrict__ as2,
    const float* __restrict__ ad2, const float* __restrict__ b2,
    float* __restrict__ Gout) {
    __shared__ __align__(16) float HA[WPB][NN * HAP];   // H1 then A1
    __shared__ __align__(16) float H2S[WPB][NN * H2P];
    __shared__ __align__(16) float PS[WPB][PSZ];        // unnormalized exp rows
    __shared__ float sdS[WPB][2 * NN];                  // src/dst dots
    __shared__ float smS[WPB][NN];                      // per-dst exp sums
    __shared__ __align__(16) float a1S[2 * HD];
    __shared__ __align__(16) float a2S[2 * FD];
    __shared__ int esS[NE], edS[NE];

    const int tid = threadIdx.x;
    const int wv = tid >> 6;
    const int lane = tid & 63;
    float* HAw = HA[wv];
    float* H2w = H2S[wv];
    float* Pw = PS[wv];
    float* sdw = sdS[wv];
    float* smw = smS[wv];

    if (tid < 2 * HD) a1S[tid] = (tid < HD) ? as1[tid] : ad1[tid - HD];
    if (tid < 2 * FD) a2S[tid] = (tid < FD) ? as2[tid] : ad2[tid - FD];
    // edge staging: robust to int64 (lo/hi dword pairs) or int32 delivery
    if (tid < 56) {
        int e64 = 1;
        for (int i = 0; i < 8; i++)
            if (ei[2 * i + 1] != 0 || (uu32)ei[2 * i] >= (uu32)NN) e64 = 0;
        esS[tid] = e64 ? ei[2 * tid] : ei[tid];
        edS[tid] = e64 ? ei[112 + 2 * tid] : ei[56 + tid];
    } else if (tid < NE) {
        esS[tid] = tid - 56;   // self loops
        edS[tid] = tid - 56;
    }

    // per-lane resident weights
    float w1r[FD];
#pragma unroll
    for (int f = 0; f < FD; f++) w1r[f] = W1[f * HD + lane];
    const float b1r = b1[lane];
    const int f2 = lane % FD;
    const int g2 = lane / FD;      // 0,1 active for 24-wide stages
    float w2r[HD];
#pragma unroll
    for (int k = 0; k < HD; k++) w2r[k] = W2[k * FD + f2];
    const float b2r = b2[f2];
    __syncthreads();   // the ONE block barrier: cross-wave staged a1S/a2S/es/ed
    // edge ownership: edge0 = lane (0..63); lanes 0..5 also own 64..69
    const bool ex = (lane < NE - 64);
    const int s0 = esS[lane], d0 = edS[lane];
    const int s1 = esS[ex ? 64 + lane : 0], d1 = edS[ex ? 64 + lane : 0];

    const int gw = blockIdx.x * WPB + wv;
#pragma unroll 1
    for (int t = 0; t < SPW; t++) {
        const size_t b = (size_t)gw * SPW + t;
        // ---- 1. X[b] per-lane into regs (coalesced); no LDS staging ----
        const float* __restrict__ xb = x + b * (NN * FD);
        float xr[6];
        xr[0] = xb[lane];
        xr[1] = xb[64 + lane];
        xr[2] = xb[128 + lane];
        xr[3] = xb[192 + lane];
        xr[4] = xb[256 + lane];
        xr[5] = (lane < NN * FD - 320) ? xb[320 + lane] : 0.0f;
        // ---- 2. H1 = X @ W1 (lane owns hidden col); X via readlane ----
        float acc[NN];
#pragma unroll
        for (int n = 0; n < NN; n++) acc[n] = 0.0f;
#pragma unroll
        for (int f = 0; f < FD; f++) {
#pragma unroll
            for (int n = 0; n < NN; n++) {
                const int i = f * NN + n;          // compile-time
                acc[n] = fmaf(rdl(xr[i >> 6], i & 63), w1r[f], acc[n]);
            }
        }
#pragma unroll
        for (int n = 0; n < NN; n++) HAw[n * HAP + lane] = acc[n];
        WSYNC();
        // ---- 3. src/dst dots (28 lanes) + zero P/sums ----
        if (lane < 2 * NN) {
            const int v = (lane >= NN) ? 1 : 0;
            const int n2 = lane - v * NN;
            float s = 0.0f;
#pragma unroll
            for (int k = 0; k < 16; k++) {
                float4 h4 = *(const float4*)&HAw[n2 * HAP + 4 * k];
                float4 a4 = *(const float4*)&a1S[v * HD + 4 * k];
                s = fmaf(h4.x, a4.x, s); s = fmaf(h4.y, a4.y, s);
                s = fmaf(h4.z, a4.z, s); s = fmaf(h4.w, a4.w, s);
            }
            sdw[v * NN + n2] = s;
        }
        if (lane < PSZ / 4)
            *(float4*)&Pw[lane * 4] = make_float4(0.f, 0.f, 0.f, 0.f);
        if (lane < NN) smw[lane] = 0.0f;
        WSYNC();
        // ---- 4. softmax1 (shift-invariant, no max pass: |alpha| << 88) ----
        {
            float a = sdw[s0] + sdw[NN + d0];
            a = a > 0.0f ? a : 0.2f * a;               // leaky_relu(0.2)
            float e0 = __expf(a);
            atomicAdd(&smw[d0], e0);
            atomicAdd(&Pw[d0 * 16 + s0], e0);          // unnormalized
            if (ex) {
                a = sdw[s1] + sdw[NN + d1];
                a = a > 0.0f ? a : 0.2f * a;
                float e1 = __expf(a);
                atomicAdd(&smw[d1], e1);
                atomicAdd(&Pw[d1 * 16 + s1], e1);
            }
        }
        WSYNC();
        // ---- 5. A1 = ELU(P @ H1 / sum + b1); P via rdl gather ----
        const float pr0 = Pw[lane];
        const float pr1 = Pw[64 + lane];
        const float pr2 = Pw[128 + lane];
        const float pr3 = (lane < PSZ - 192) ? Pw[192 + lane] : 0.0f;
        const float smr = (lane < NN) ? smw[lane] : 1.0f;
        float acc2[NN];
#pragma unroll
        for (int n = 0; n < NN; n++) {
            float a = 0.0f;
#pragma unroll
            for (int k = 0; k < NN; k++) {
                const int i = n * 16 + k;          // compile-time
                const float pv = (i < 64) ? rdl(pr0, i) :
                                 (i < 128) ? rdl(pr1, i - 64) :
                                 (i < 192) ? rdl(pr2, i - 128) :
                                             rdl(pr3, i - 192);
                a = fmaf(pv, acc[k], a);
            }
            a = __fdividef(a, rdl(smr, n)) + b1r;
            acc2[n] = a > 0.0f ? a : (__expf(a) - 1.0f);   // ELU
        }
#pragma unroll
        for (int n = 0; n < NN; n++) HAw[n * HAP + lane] = acc2[n];
        WSYNC();
        // ---- 6. H2 = A1 @ W2 : lane (g2,f2) covers 7 nodes ----
        if (g2 < 2) {
#pragma unroll
            for (int i = 0; i < 7; i++) {
                const int n = g2 + 2 * i;
                float a = 0.0f;
#pragma unroll
                for (int k4 = 0; k4 < 16; k4++) {
                    float4 v4 = *(const float4*)&HAw[n * HAP + 4 * k4];
                    a = fmaf(v4.x, w2r[4 * k4 + 0], a);
                    a = fmaf(v4.y, w2r[4 * k4 + 1], a);
                    a = fmaf(v4.z, w2r[4 * k4 + 2], a);
                    a = fmaf(v4.w, w2r[4 * k4 + 3], a);
                }
                H2w[n * H2P + f2] = a;
            }
        }
        WSYNC();
        // ---- 7. conv2 dots (28 lanes) + zero P/sums ----
        if (lane < 2 * NN) {
            const int v = (lane >= NN) ? 1 : 0;
            const int n2 = lane - v * NN;
            float s = 0.0f;
#pragma unroll
            for (int q = 0; q < 6; q++) {
                float4 h4 = *(const float4*)&H2w[n2 * H2P + 4 * q];
                float4 a4 = *(const float4*)&a2S[v * FD + 4 * q];
                s = fmaf(h4.x, a4.x, s); s = fmaf(h4.y, a4.y, s);
                s = fmaf(h4.z, a4.z, s); s = fmaf(h4.w, a4.w, s);
            }
            sdw[v * NN + n2] = s;
        }
        if (lane < PSZ / 4)
            *(float4*)&Pw[lane * 4] = make_float4(0.f, 0.f, 0.f, 0.f);
        if (lane < NN) smw[lane] = 0.0f;
        WSYNC();
        // ---- 8. softmax2 ----
        {
            float a = sdw[s0] + sdw[NN + d0];
            a = a > 0.0f ? a : 0.2f * a;
            float e0 = __expf(a);
            atomicAdd(&smw[d0], e0);
            atomicAdd(&Pw[d0 * 16 + s0], e0);
            if (ex) {
                a = sdw[s1] + sdw[NN + d1];
                a = a > 0.0f ? a : 0.2f * a;
                float e1 = __expf(a);
                atomicAdd(&smw[d1], e1);
                atomicAdd(&Pw[d1 * 16 + s1], e1);
            }
        }
        WSYNC();
        // ---- 9. G = P2 @ H2 / sum + b2 -> d_out [14][B][24] ----
        if (g2 < 2) {
            float h2c[NN];
#pragma unroll
            for (int k = 0; k < NN; k++) h2c[k] = H2w[k * H2P + f2];
#pragma unroll
            for (int i = 0; i < 7; i++) {
                const int n = g2 + 2 * i;
                float a = 0.0f;
#pragma unroll
                for (int k4 = 0; k4 < 3; k4++) {
                    float4 p4 = *(const float4*)&Pw[n * 16 + 4 * k4];
                    a = fmaf(p4.x, h2c[4 * k4 + 0], a);
                    a = fmaf(p4.y, h2c[4 * k4 + 1], a);
                    a = fmaf(p4.z, h2c[4 * k4 + 2], a);
                    a = fmaf(p4.w, h2c[4 * k4 + 3], a);
                }
                float4 p4 = *(const float4*)&Pw[n * 16 + 12];
                a = fmaf(p4.x, h2c[12], a);
                a = fmaf(p4.y, h2c[13], a);
                Gout[((size_t)n * BB + b) * FD + f2] =
                    __fdividef(a, smw[n]) + b2r;
            }
        }
        WSYNC();   // protect reused LDS before next sample (wave-local)
    }
}

// MLP stage, in place on d_out — round-0 structure (best measured: 133 us)
// with three low-risk tweaks: (a) g-loads issued BEFORE the staging barrier
// (compiler can't hoist globals across __syncthreads; hides ~600cy HBM
// latency under staging), (b) float4 bias reads (-72 LDS instr/wave),
// (c) unroll 2 on j4 for cross-iteration ds_read pipelining (~4.5KB body,
// I$-resident; the 50KB full-unroll variant measured I$-bound).
__global__ __launch_bounds__(256) void mlp_k(
    const float* __restrict__ fc1w, const float* __restrict__ fc1b,
    const float* __restrict__ fc2w, const float* __restrict__ fc2b,
    float* __restrict__ gio) {
    __shared__ __align__(16) float W1L[FD * HD];
    __shared__ __align__(16) float W2L[HD * FD];
    __shared__ __align__(16) float B1L[HD];
    __shared__ __align__(16) float B2L[FD];

    const int t = threadIdx.x;
    const int n = blockIdx.x >> 7;             // 128 blocks per node
    const int b0 = (blockIdx.x & 127) * 256;

    // issue the per-thread activation loads FIRST (latency hidden by staging)
    const size_t base = ((size_t)n * BB + b0 + t) * FD;
    float g[FD];
#pragma unroll
    for (int q = 0; q < 6; q++)
        *(float4*)&g[4 * q] = *(const float4*)&gio[base + 4 * q];

    const float4* w1p = (const float4*)(fc1w + (size_t)n * (FD * HD));
    const float4* w2p = (const float4*)(fc2w + (size_t)n * (HD * FD));
    for (int i = t; i < 384; i += 256) {
        *(float4*)&W1L[4 * i] = w1p[i];
        *(float4*)&W2L[4 * i] = w2p[i];
    }
    if (t < HD) B1L[t] = fc1b[n * HD + t];
    if (t < FD) B2L[t] = fc2b[n * FD + t];
    __syncthreads();

    float o[FD];
#pragma unroll
    for (int q = 0; q < 6; q++) {
        float4 b4 = *(const float4*)&B2L[4 * q];
        o[4 * q + 0] = b4.x; o[4 * q + 1] = b4.y;
        o[4 * q + 2] = b4.z; o[4 * q + 3] = b4.w;
    }

#pragma unroll 2
    for (int j4 = 0; j4 < 16; j4++) {
        float4 b14 = *(const float4*)&B1L[4 * j4];
        float h0 = b14.x, h1 = b14.y, h2 = b14.z, h3 = b14.w;
#pragma unroll
        for (int f = 0; f < FD; f++) {
            float4 w4 = *(const float4*)&W1L[f * HD + 4 * j4];   // broadcast
            h0 = fmaf(g[f], w4.x, h0);
            h1 = fmaf(g[f], w4.y, h1);
            h2 = fmaf(g[f], w4.z, h2);
            h3 = fmaf(g[f], w4.w, h3);
        }
        h0 = fmaxf(h0, 0.f); h1 = fmaxf(h1, 0.f);
        h2 = fmaxf(h2, 0.f); h3 = fmaxf(h3, 0.f);
        float hv[4] = {h0, h1, h2, h3};
#pragma unroll
        for (int u2 = 0; u2 < 4; u2++) {
            const int j = 4 * j4 + u2;
#pragma unroll
            for (int f4 = 0; f4 < 6; f4++) {
                float4 w4 = *(const float4*)&W2L[j * FD + 4 * f4];   // broadcast
                o[4 * f4 + 0] = fmaf(hv[u2], w4.x, o[4 * f4 + 0]);
                o[4 * f4 + 1] = fmaf(hv[u2], w4.y, o[4 * f4 + 1]);
                o[4 * f4 + 2] = fmaf(hv[u2], w4.z, o[4 * f4 + 2]);
                o[4 * f4 + 3] = fmaf(hv[u2], w4.w, o[4 * f4 + 3]);
            }
        }
    }
#pragma unroll
    for (int q = 0; q < 6; q++)
        *(float4*)&gio[base + 4 * q] = *(const float4*)&o[4 * q];
}

extern "C" void kernel_launch(void* const* d_in, const int* in_sizes, int n_in,
                              void* d_out, int out_size, void* d_ws, size_t ws_size,
                              hipStream_t stream) {
    (void)in_sizes; (void)n_in; (void)out_size; (void)d_ws; (void)ws_size;
    const float* x    = (const float*)d_in[0];
    const int*   ei   = (const int*)d_in[1];
    const float* W1   = (const float*)d_in[2];
    const float* as1  = (const float*)d_in[3];
    const float* ad1  = (const float*)d_in[4];
    const float* b1   = (const float*)d_in[5];
    const float* W2   = (const float*)d_in[6];
    const float* as2  = (const float*)d_in[7];
    const float* ad2  = (const float*)d_in[8];
    const float* b2   = (const float*)d_in[9];
    const float* fc1w = (const float*)d_in[10];
    const float* fc1b = (const float*)d_in[11];
    const float* fc2w = (const float*)d_in[12];
    const float* fc2b = (const float*)d_in[13];
    float* gio = (float*)d_out;   // G staged in d_out, MLP rewrites in place

    gat_k<<<dim3(K1_BLOCKS), dim3(256), 0, stream>>>(
        x, ei, W1, as1, ad1, b1, W2, as2, ad2, b2, gio);
    mlp_k<<<dim3(K2_BLOCKS), dim3(256), 0, stream>>>(
        fc1w, fc1b, fc2w, fc2b, gio);
}